// Round 1
// baseline (115.437 us; speedup 1.0000x reference)
//
#include <hip/hip_runtime.h>

// QuantumPINN: out = a*z + b where z = <psi| Z |psi>, psi = U(weights) RY(x)|0>.
// Algebraic collapse: out = K0 + K1*cos(x) + K2*sin(x), K* derived from the
// 2x2 weight-only unitary U (6 floats). Pure streaming elementwise kernel.

struct cplx { float re, im; };

__device__ inline cplx cmul(cplx p, cplx q) {
    cplx r;
    r.re = p.re * q.re - p.im * q.im;
    r.im = p.re * q.im + p.im * q.re;
    return r;
}
__device__ inline cplx cadd(cplx p, cplx q) { return cplx{p.re + q.re, p.im + q.im}; }

__global__ __launch_bounds__(256) void qpinn_kernel(
    const float* __restrict__ x, const float* __restrict__ w,
    const float* __restrict__ pa, const float* __restrict__ pb,
    float* __restrict__ out, int n4) {

    // ---- per-thread (uniform) coefficient computation from 6 weights ----
    const float a = pa[0];
    const float b = pb[0];

    // U = I
    cplx U00{1.f, 0.f}, U01{0.f, 0.f}, U10{0.f, 0.f}, U11{1.f, 0.f};

    #pragma unroll
    for (int l = 0; l < 2; ++l) {
        const float h0 = 0.5f * w[3 * l + 0];
        const float h1 = 0.5f * w[3 * l + 1];
        const float h2 = 0.5f * w[3 * l + 2];
        float c0, s0, c1, s1, c2, s2;
        __sincosf(h0, &s0, &c0);
        __sincosf(h1, &s1, &c1);
        __sincosf(h2, &s2, &c2);

        // RX = [[c0, -i s0], [-i s0, c0]]
        cplx X00{c0, 0.f}, X01{0.f, -s0}, X10{0.f, -s0}, X11{c0, 0.f};
        // RY = [[c1, -s1], [s1, c1]] (real)
        cplx Y00{c1, 0.f}, Y01{-s1, 0.f}, Y10{s1, 0.f}, Y11{c1, 0.f};
        // RYX = RY @ RX
        cplx A00 = cadd(cmul(Y00, X00), cmul(Y01, X10));
        cplx A01 = cadd(cmul(Y00, X01), cmul(Y01, X11));
        cplx A10 = cadd(cmul(Y10, X00), cmul(Y11, X10));
        cplx A11 = cadd(cmul(Y10, X01), cmul(Y11, X11));
        // RZ = diag(e^{-i h2}, e^{+i h2})
        cplx zm{c2, -s2}, zp{c2, s2};
        cplx L00 = cmul(zm, A00), L01 = cmul(zm, A01);
        cplx L10 = cmul(zp, A10), L11 = cmul(zp, A11);
        // U = L @ U
        cplx n00 = cadd(cmul(L00, U00), cmul(L01, U10));
        cplx n01 = cadd(cmul(L00, U01), cmul(L01, U11));
        cplx n10 = cadd(cmul(L10, U00), cmul(L11, U10));
        cplx n11 = cadd(cmul(L10, U01), cmul(L11, U11));
        U00 = n00; U01 = n01; U10 = n10; U11 = n11;
    }

    const float A = (U00.re * U00.re + U00.im * U00.im) - (U10.re * U10.re + U10.im * U10.im);
    const float B = (U01.re * U01.re + U01.im * U01.im) - (U11.re * U11.re + U11.im * U11.im);
    const float C = 2.f * ((U00.re * U01.re + U00.im * U01.im) -
                           (U10.re * U11.re + U10.im * U11.im));

    const float K0 = fmaf(a, 0.5f * (A + B), b);
    const float K1 = a * 0.5f * (A - B);
    const float K2 = a * 0.5f * C;

    // ---- streaming elementwise: out = K0 + K1*cos(x) + K2*sin(x) ----
    const float4* __restrict__ x4 = (const float4*)x;
    float4* __restrict__ o4 = (float4*)out;

    const int stride = gridDim.x * blockDim.x;
    for (int i = blockIdx.x * blockDim.x + threadIdx.x; i < n4; i += stride) {
        float4 v = x4[i];
        float4 r;
        float sx, cx;
        __sincosf(v.x, &sx, &cx); r.x = fmaf(K1, cx, fmaf(K2, sx, K0));
        __sincosf(v.y, &sx, &cx); r.y = fmaf(K1, cx, fmaf(K2, sx, K0));
        __sincosf(v.z, &sx, &cx); r.z = fmaf(K1, cx, fmaf(K2, sx, K0));
        __sincosf(v.w, &sx, &cx); r.w = fmaf(K1, cx, fmaf(K2, sx, K0));
        o4[i] = r;
    }
}

extern "C" void kernel_launch(void* const* d_in, const int* in_sizes, int n_in,
                              void* d_out, int out_size, void* d_ws, size_t ws_size,
                              hipStream_t stream) {
    const float* x = (const float*)d_in[0];
    const float* w = (const float*)d_in[1];   // [L=2, 3]
    const float* a = (const float*)d_in[2];
    const float* b = (const float*)d_in[3];
    float* out = (float*)d_out;

    const int n = in_sizes[0];       // 16777216, divisible by 4
    const int n4 = n / 4;            // 4194304 float4 elements
    const int block = 256;
    // ~2 float4 per thread: 8192 blocks -> 32 blocks/CU, plenty of waves
    const int grid = (n4 + block * 2 - 1) / (block * 2);

    qpinn_kernel<<<grid, block, 0, stream>>>(x, w, a, b, out, n4);
}